// Round 15
// baseline (56.243 us; speedup 1.0000x reference)
//
#include <hip/hip_runtime.h>

// Delay-logistic DDE, forward Euler, d independent scalar components.
// x_{i+1} = x_i * m_i,  m_i = (1+a) - a*th1*y_i;  y_i = x(i-100) (hist = x_0).
// Output: out[j*(N+1) + t] = x_t  (row-major [d, N+1]).
//
// Round 15: FULL-ROW-LINEAR drain. r12-r14 plateau at 31-33us with ~4.2TB/s
// effective write BW vs fill's 6.5+: all wrote 400B chunks strided 4004B
// (new DRAM page per chunk, 2 partial 128B lines per chunk). Here each
// 1-wave block owns 8 components, integrates all 1000 steps (lanes 0-7,
// serial chain ~2us) staging every column into an [8][1001] LDS image
// (32,032B -> 5 blocks/CU), then ALL 64 lanes drain the block's contiguous
// 32,032B global span with dwordx4 linear stores (1KB/instr, full lines,
// sequential pages — exactly the fill pattern that hits 87% of peak).
// Final column t=1000 is staged into the image too: no scattered stores.
// Overlap comes from 5 independent blocks/CU x ~3 dispatch generations.
//
// Kept verified machinery: h[100] in VGPRs via macro-LITERAL indices +
// (64,1) (rounds 2-5: default occupancy target force-spills h to scratch);
// LDS_ORDER fence (lgkmcnt-only + sched_barrier + memory clobber) at the
// cross-lane stage->drain boundary (round 6: compiler legally reorders
// cross-lane LDS); batched ds_read->store in the drain (round 14).

constexpr int NT   = 1000;          // N steps (setup_inputs: N=1000)
constexpr int NTAU = 100;           // delay interval
constexpr int NGRP = NT / NTAU;     // 10 tiles
constexpr int NP1  = NT + 1;        // 1001 columns per row
constexpr int COMP = 8;             // components per block (lanes 0-7 compute)
constexpr int SPAN = COMP * NP1;    // 8008 dwords = 32,032 B contiguous span
constexpr int NF4  = SPAN / 4;      // 2002 float4s
constexpr int NWI  = NF4 / 64;      // 31 full wave-iterations
constexpr int TAIL = NF4 - NWI*64;  // 18 float4s (lanes < 18)

// Literal-index repetition macros (SROA-proof: every h index is a literal).
#define R5(F,B)   F(B) F((B)+1) F((B)+2) F((B)+3) F((B)+4)
#define R25(F,B)  R5(F,B) R5(F,(B)+5) R5(F,(B)+10) R5(F,(B)+15) R5(F,(B)+20)
#define R50(F,B)  R25(F,B) R25(F,(B)+25)
#define R100(F)   R50(F,0) R50(F,50)

// LDS-only ordering point: pins compiler order and drains the DS pipe.
// NEVER waits on vmcnt -> global stores keep streaming.
#define LDS_ORDER() do {                                    \
    __builtin_amdgcn_sched_barrier(0);                      \
    asm volatile("s_waitcnt lgkmcnt(0)" ::: "memory");      \
    __builtin_amdgcn_sched_barrier(0);                      \
} while (0)

__global__ __launch_bounds__(64, 1)    // min 1 wave/EU: full VGPR budget
void ndde_kernel(const float* __restrict__ x0,
                 const float* __restrict__ tau,
                 const float* __restrict__ params,
                 float* __restrict__ out)
{
    __shared__ __align__(16) float hold[SPAN];   // [8][1001] row image, 32,032 B
    const int lane  = threadIdx.x;
    const int jbase = (int)blockIdx.x * COMP;

    const float dt = 0.01f * tau[0];
    const float a  = dt * params[0];        // dt * theta0
    const float q  = -(a * params[1]);      // -dt*theta0*theta1
    const float p  = 1.0f + a;

    // All 64 lanes compute (lanes >= 8 redundantly mirror lane&7: keeps the
    // compute unmasked; only lanes 0-7 stage). No OOB: index clamped.
    float x = x0[jbase + (lane & (COMP - 1))];
    float h[NTAU];                          // history ring; lives in VGPRs
#define INIT_H(K) h[(K)] = x;
    R100(INIT_H)

#define STEP(K) { const float y_ = h[(K)]; h[(K)] = x; x *= fmaf(q, y_, p); }
#define STG(K)  bp[(K)] = h[(K)];

#pragma clang loop unroll(disable)          // ~300-instr tile body, I-cache-resident
    for (int g = 0; g < NGRP; ++g) {
        R100(STEP)                          // h[k] = x_{100g+k}
        if (lane < COMP) {                  // stage tile into the row image
            float* bp = &hold[lane * NP1 + g * NTAU];
            R100(STG)                       // banks (9*lane + c) % 32: conflict-free
        }
    }
    if (lane < COMP)
        hold[lane * NP1 + NT] = x;          // final column t = N in the image

    LDS_ORDER();                            // cross-lane: stage -> drain

    // Linear drain: the LDS image IS the global span. 1KB per instruction.
    const float4* ls = (const float4*)hold;
    float4* gd = (float4*)(out + (size_t)jbase * NP1);   // 16B-aligned: 8*4004%16==0

    // Batch 4 reads then 4 stores (one lgkm wait per batch, round-14 lesson).
    int i = 0;
    for (; i + 4 <= NWI; i += 4) {
        float4 v0 = ls[(i + 0) * 64 + lane];
        float4 v1 = ls[(i + 1) * 64 + lane];
        float4 v2 = ls[(i + 2) * 64 + lane];
        float4 v3 = ls[(i + 3) * 64 + lane];
        gd[(i + 0) * 64 + lane] = v0;
        gd[(i + 1) * 64 + lane] = v1;
        gd[(i + 2) * 64 + lane] = v2;
        gd[(i + 3) * 64 + lane] = v3;
    }
    for (; i < NWI; ++i) {
        float4 v = ls[i * 64 + lane];
        gd[i * 64 + lane] = v;
    }
    if (lane < TAIL) {                      // last 18 float4s
        float4 v = ls[NWI * 64 + lane];
        gd[NWI * 64 + lane] = v;
    }
}

extern "C" void kernel_launch(void* const* d_in, const int* in_sizes, int n_in,
                              void* d_out, int out_size, void* d_ws, size_t ws_size,
                              hipStream_t stream) {
    const float* x0     = (const float*)d_in[0];
    const float* tau    = (const float*)d_in[1];
    const float* params = (const float*)d_in[2];
    float* out = (float*)d_out;
    const int d = in_sizes[0];              // 32768
    const int nblocks = d / COMP;           // 4096 one-wave blocks
    ndde_kernel<<<nblocks, 64, 0, stream>>>(x0, tau, params, out);
}

// Round 16
// 31.512 us; speedup vs baseline: 1.7848x; 1.7848x over previous
//
#include <hip/hip_runtime.h>

// Delay-logistic DDE, forward Euler, d independent scalar components.
// x_{i+1} = x_i * m_i,  m_i = (1+a) - a*th1*y_i;  y_i = x(i-100) (hist = x_0).
// Output: out[j*(N+1) + t] = x_t  (row-major [d, N+1]).
//
// Round 16: DENSITY A/B on the r14 skeleton. r12-r14 plateau at 31-33us,
// ~4.2TB/s effective vs fill's 6.8. With ~256B HBM channel interleave, DRAM
// page efficiency follows the DENSITY of the write footprint per span: a
// 100-col tile drain puts 25.6KB into a 256KB span (10%). Here the producer
// publishes TWO tiles per phase: 200-col phases, 800B row-chunks, 51.2KB
// per phase over the same span = 20% density, half the phase count.
// Everything else is the verified r14 machinery:
//  - producer/consumer waves (1P+3C), zero recompute, block owns 64 rows;
//  - h[100] in VGPRs: macro-LITERAL indices + (256,1) (rounds 2-5: default
//    occupancy target force-spills h to scratch);
//  - LDS flag sync + lgkmcnt-ONLY fences (r6: cross-lane LDS needs explicit
//    ordering; vmcnt never drained in-loop -> stores stream);
//  - batched ds_read->store drain, contiguous row ranges per consumer (r14).

constexpr int NT   = 1000;          // N steps (setup_inputs: N=1000)
constexpr int NTAU = 100;           // delay = ring size
constexpr int NPH  = 5;             // phases (2 tiles each)
constexpr int PCOL = 200;           // columns per phase
constexpr int NP1  = NT + 1;        // 1001 columns per row
constexpr int COMP = 64;            // components per block (= producer lanes)
constexpr int LSTR = PCOL + 1;      // 201 dwords: odd stride -> conflict-free
constexpr int NCW  = 3;             // consumer waves

// Literal-index repetition macros (SROA-proof: every h index is a literal).
#define R5(F,B)   F(B) F((B)+1) F((B)+2) F((B)+3) F((B)+4)
#define R25(F,B)  R5(F,B) R5(F,(B)+5) R5(F,(B)+10) R5(F,(B)+15) R5(F,(B)+20)
#define R50(F,B)  R25(F,B) R25(F,(B)+25)
#define R100(F)   R50(F,0) R50(F,50)

// LDS-only ordering point: pins compiler order and drains the DS pipe.
// NEVER waits on vmcnt -> global stores keep streaming.
#define LDS_ORDER() do {                                    \
    __builtin_amdgcn_sched_barrier(0);                      \
    asm volatile("s_waitcnt lgkmcnt(0)" ::: "memory");      \
    __builtin_amdgcn_sched_barrier(0);                      \
} while (0)

__global__ __launch_bounds__(256, 1)   // min 1 wave/EU: full VGPR budget
void ndde_kernel(const float* __restrict__ x0,
                 const float* __restrict__ tau,
                 const float* __restrict__ params,
                 float* __restrict__ out)
{
    __shared__ float buf[2][COMP][LSTR];   // 102,912 B double-buffered 2-tile image
    __shared__ int   prodf;                // phases published
    __shared__ int   consf[NCW];           // phases consumed, per consumer wave
    const int tid  = threadIdx.x;
    const int wid  = tid >> 6;             // 0 = producer, 1..3 = consumers
    const int lane = tid & 63;
    const int jbase = (int)blockIdx.x * COMP;

    const float dt = 0.01f * tau[0];
    const float a  = dt * params[0];        // dt * theta0
    const float q  = -(a * params[1]);      // -dt*theta0*theta1
    const float p  = 1.0f + a;

    if (tid == 0) { prodf = 0; consf[0] = 0; consf[1] = 0; consf[2] = 0; }
    __syncthreads();                        // flag init only (once; queues empty)

    volatile int* vprod = &prodf;
    volatile int* vcons = consf;

    if (wid == 0) {
        // ---------------- producer ----------------
        float x = x0[jbase + lane];
        float h[NTAU];                      // history ring; lives in VGPRs
#define INIT_H(K) h[(K)] = x;
        R100(INIT_H)
#define STEP(K) { const float y_ = h[(K)]; h[(K)] = x; x *= fmaf(q, y_, p); }
#define STG0(K) bp[(K)] = h[(K)];          // tile -> phase cols 0..99
#define STG1(K) bp[100+(K)] = h[(K)];      // tile -> phase cols 100..199

#pragma clang loop unroll(disable)          // keep body I-cache-resident
        for (int ph = 0; ph < NPH; ++ph) {
            if (ph >= 2) {                  // buf[ph&1] holds phase ph-2: wait consumed
                while (vcons[0] < ph - 1 || vcons[1] < ph - 1 || vcons[2] < ph - 1)
                    __builtin_amdgcn_s_sleep(1);
                LDS_ORDER();                // poll -> overwrite (cross-wave WAR)
            }
            float* bp = &buf[ph & 1][lane][0];
            R100(STEP)                      // h[k] = x_{200ph+k}
            R100(STG0)
            R100(STEP)                      // h[k] = x_{200ph+100+k}
            R100(STG1)
            LDS_ORDER();                    // data writes drain before flag (RAW)
            *vprod = ph + 1;                // publish phase
        }
        // Final column t = N: x = x_1000.
        out[(jbase + lane) * NP1 + NT] = x;
    } else {
        // ---------------- consumers ----------------
        const int cw    = wid - 1;
        const int start = (cw == 0) ? 0 : (cw == 1) ? 22 : 43;
        const int cnt   = (cw == 0) ? 22 : 21;           // 22+21+21 = 64
        const int lane8 = (lane < 8) ? lane : 7;         // clamp: tail store lanes
        float* gpb = out + (jbase + start) * NP1 + lane;

#pragma clang loop unroll(disable)
        for (int ph = 0; ph < NPH; ++ph) {
            while (*vprod < ph + 1)         // wait for phase
                __builtin_amdgcn_s_sleep(1);
            LDS_ORDER();                    // poll -> data reads (cross-wave RAW)
            const float* bb = &buf[ph & 1][start][0];
            float* gp = gpb + ph * PCOL;

            // 2-row batches: 8 independent ds_reads, then 8 stores.
            // Row chunk = 800B contiguous (3 x 256B + 32B), address order.
            for (int r = 0; r < cnt; r += 2) {
                const int r1 = (r + 1 < cnt) ? r + 1 : r;   // safe dup on odd tail
                const float* la = bb + r  * LSTR;
                const float* lb = bb + r1 * LSTR;
                float a0 = la[lane], a1 = la[64 + lane], a2 = la[128 + lane];
                float a3 = la[192 + lane8];
                float b0 = lb[lane], b1 = lb[64 + lane], b2 = lb[128 + lane];
                float b3 = lb[192 + lane8];
                float* ra = gp + r  * NP1;
                float* rb = gp + r1 * NP1;
                ra[0] = a0; ra[64] = a1; ra[128] = a2;
                if (lane < 8) ra[192] = a3;
                if (r1 != r) {
                    rb[0] = b0; rb[64] = b1; rb[128] = b2;
                    if (lane < 8) rb[192] = b3;
                }
            }
            LDS_ORDER();                    // ds_reads drained (stores NOT waited)
            vcons[cw] = ph + 1;             // release buf[ph&1]
        }
    }
}

extern "C" void kernel_launch(void* const* d_in, const int* in_sizes, int n_in,
                              void* d_out, int out_size, void* d_ws, size_t ws_size,
                              hipStream_t stream) {
    const float* x0     = (const float*)d_in[0];
    const float* tau    = (const float*)d_in[1];
    const float* params = (const float*)d_in[2];
    float* out = (float*)d_out;
    const int d = in_sizes[0];              // 32768
    const int nblocks = d / COMP;           // 512 blocks x 256 threads
    ndde_kernel<<<nblocks, 256, 0, stream>>>(x0, tau, params, out);
}